// Round 11
// baseline (112.365 us; speedup 1.0000x reference)
//
#include <hip/hip_runtime.h>
#include <hip/hip_bf16.h>

#define B_    4
#define S_    2048
#define HID_  512
#define NH_   8
#define HD_   64
#define MAXREL 512
#define M_    (B_ * S_)   // 8192 tokens

#define LOG2E 1.44269504f
#define SCALE_Q (0.125f * LOG2E)   // folded into Q at projection time

typedef __attribute__((ext_vector_type(8))) short bf8;            // 8 bf16 (MFMA A/B frag)
typedef __attribute__((ext_vector_type(4))) float f4;             // 16x16 C/D frag
typedef __attribute__((ext_vector_type(16))) float f16f;          // 32x32 C/D frag

static __device__ __forceinline__ unsigned short f2bf(float f) {
    union { float f; unsigned int u; } v; v.f = f;
    unsigned int u = v.u;
    unsigned int r = (u + 0x7FFFu + ((u >> 16) & 1u)) >> 16;   // round-nearest-even
    return (unsigned short)r;
}

static __device__ __forceinline__ float ex2(float x) {   // raw v_exp_f32 (base-2)
    float r; asm("v_exp_f32 %0, %1" : "=v"(r) : "v"(x)); return r;
}

// async global->LDS, 16B per lane; dest = wave-uniform base + lane*16 (linear)
static __device__ __forceinline__ void gload16(const void* g, void* l) {
    __builtin_amdgcn_global_load_lds(
        (const __attribute__((address_space(1))) unsigned int*)g,
        (__attribute__((address_space(3))) unsigned int*)l, 16, 0, 0);
}

static __device__ __forceinline__ bf8 mkbf8(unsigned a, unsigned b, unsigned c, unsigned d) {
    uint4 u = make_uint4(a, b, c, d);
    return *(bf8*)&u;
}

#define MFMA16(a, b, c) __builtin_amdgcn_mfma_f32_16x16x32_bf16((a), (b), (c), 0, 0, 0)
#define MFMA32(a, b, c) __builtin_amdgcn_mfma_f32_32x32x16_bf16((a), (b), (c), 0, 0, 0)

// ---------------- cast hidden_states fp32 -> bf16 ----------------
__global__ void k_cast_hs(const float* __restrict__ src, unsigned short* __restrict__ dst, int n4) {
    int i = blockIdx.x * blockDim.x + threadIdx.x;
    if (i >= n4) return;
    float4 v = ((const float4*)src)[i];
    ushort4 o;
    o.x = f2bf(v.x); o.y = f2bf(v.y); o.z = f2bf(v.z); o.w = f2bf(v.w);
    ((ushort4*)dst)[i] = o;
}

// ---------------- mask -> additive form (0 attend / -3e38 masked) ----------------
__global__ void k_prep_mask(const float* __restrict__ mask, float* __restrict__ maskadd) {
    int i = blockIdx.x * blockDim.x + threadIdx.x;
    if (i < M_) maskadd[i] = (1.0f - mask[i]) * -3.0e38f;
}

// ---------------- transpose + cast 4 weights (LDS 32x32 tiles) ----------------
__global__ void k_transpose_w4(const float* __restrict__ W0, const float* __restrict__ W1,
                               const float* __restrict__ W2, const float* __restrict__ W3,
                               unsigned short* __restrict__ T0, unsigned short* __restrict__ T1,
                               unsigned short* __restrict__ T2, unsigned short* __restrict__ T3) {
    __shared__ float tile[32][33];
    const int z = blockIdx.z;
    const float* W = (z == 0) ? W0 : (z == 1) ? W1 : (z == 2) ? W2 : W3;
    unsigned short* T = (z == 0) ? T0 : (z == 1) ? T1 : (z == 2) ? T2 : T3;
    const int tx = threadIdx.x & 31, ty = threadIdx.x >> 5;   // 256 thr
    const int n0 = blockIdx.x * 32, k0 = blockIdx.y * 32;
    #pragma unroll
    for (int i = 0; i < 4; ++i)
        tile[ty + i * 8][tx] = W[(size_t)(k0 + ty + i * 8) * HID_ + n0 + tx];
    __syncthreads();
    #pragma unroll
    for (int i = 0; i < 4; ++i)
        T[(size_t)(n0 + ty + i * 8) * HID_ + k0 + tx] = f2bf(tile[tx][ty + i * 8]);
}

// ---------------- fused QKV GEMM: 128x128 tile, dbuf LDS via global_load_lds ----------------
__global__ __launch_bounds__(256, 3) void k_gemm_qkv(
    const unsigned short* __restrict__ Abf,
    const unsigned short* __restrict__ Wqt, const unsigned short* __restrict__ Wkt,
    const unsigned short* __restrict__ Wvt,
    const float* __restrict__ bq, const float* __restrict__ bk, const float* __restrict__ bv,
    unsigned short* __restrict__ Q, unsigned short* __restrict__ K, unsigned short* __restrict__ Vt)
{
    __shared__ unsigned short Al[2][128 * 32];
    __shared__ unsigned short Bl[2][128 * 32];

    const int t = threadIdx.x;
    const int lane = t & 63, w = t >> 6;
    const int lr = lane & 15, lg = lane >> 4;
    const int wr = w >> 1, wc = w & 1;

    const int m0 = blockIdx.x * 128;
    const int ng = blockIdx.y * 128;
    const int z = ng >> 9;
    const int n0 = ng & 511;
    const unsigned short* Wt = (z == 0) ? Wqt : ((z == 1) ? Wkt : Wvt);
    const float* bias = (z == 0) ? bq : ((z == 1) ? bk : bv);
    const float osc = (z == 0) ? SCALE_Q : 1.0f;

    const int srow = t >> 2;
    const int sc = (((t & 3) ^ ((srow >> 1) & 3))) * 8;     // swizzled source col
    const unsigned short* Ag0 = &Abf[(size_t)(m0 + srow) * HID_ + sc];
    const unsigned short* Ag1 = &Abf[(size_t)(m0 + 64 + srow) * HID_ + sc];
    const unsigned short* Bg0 = &Wt[(size_t)(n0 + srow) * HID_ + sc];
    const unsigned short* Bg1 = &Wt[(size_t)(n0 + 64 + srow) * HID_ + sc];
    char* dA0 = (char*)&Al[0][0] + w * 1024;
    char* dB0 = (char*)&Bl[0][0] + w * 1024;

    const int fx = (lr >> 1) & 3;
    int aoff[4], boff[4];
    #pragma unroll
    for (int i = 0; i < 4; ++i) {
        aoff[i] = (wr * 64 + i * 16 + lr) * 32 + ((lg ^ fx) * 8);
        boff[i] = (wc * 64 + i * 16 + lr) * 32 + ((lg ^ fx) * 8);
    }

    gload16(Ag0, dA0);
    gload16(Ag1, dA0 + 4096);
    gload16(Bg0, dB0);
    gload16(Bg1, dB0 + 4096);
    __syncthreads();

    f4 acc[4][4] = {};
    for (int kt = 0; kt < 16; ++kt) {
        const int cur = kt & 1;
        if (kt < 15) {
            const int ko = (kt + 1) * 32;
            const int bo = (cur ^ 1) * 8192;
            gload16(Ag0 + ko, dA0 + bo);
            gload16(Ag1 + ko, dA0 + bo + 4096);
            gload16(Bg0 + ko, dB0 + bo);
            gload16(Bg1 + ko, dB0 + bo + 4096);
        }
        bf8 af[4], bf_[4];
        #pragma unroll
        for (int i = 0; i < 4; ++i) {
            af[i]  = *(const bf8*)&Al[cur][aoff[i]];
            bf_[i] = *(const bf8*)&Bl[cur][boff[i]];
        }
        #pragma unroll
        for (int mi = 0; mi < 4; ++mi)
            #pragma unroll
            for (int ni = 0; ni < 4; ++ni)
                acc[mi][ni] = MFMA16(af[mi], bf_[ni], acc[mi][ni]);
        __syncthreads();
    }

    #pragma unroll
    for (int mi = 0; mi < 4; ++mi)
    #pragma unroll
    for (int ni = 0; ni < 4; ++ni) {
        const int col = n0 + wc * 64 + ni * 16 + lr;
        const int h = col >> 6, d = col & 63;
        const float bs = bias[col];
        const int row0 = m0 + wr * 64 + mi * 16 + lg * 4;
        const int b = row0 >> 11, s0 = row0 & 2047;
        if (z == 2) {
            ushort4 o;
            o.x = f2bf(acc[mi][ni][0] + bs);
            o.y = f2bf(acc[mi][ni][1] + bs);
            o.z = f2bf(acc[mi][ni][2] + bs);
            o.w = f2bf(acc[mi][ni][3] + bs);
            *(ushort4*)&Vt[(((size_t)(b * NH_ + h)) * HD_ + d) * S_ + s0] = o;
        } else {
            unsigned short* dst = (z == 0) ? Q : K;
            #pragma unroll
            for (int r = 0; r < 4; ++r) {
                float v = (acc[mi][ni][r] + bs) * osc;
                dst[(((size_t)(b * NH_ + h)) * S_ + s0 + r) * HD_ + d] = f2bf(v);
            }
        }
    }
}

// ---------------- output projection GEMM: 128x128 tile, 512 threads ----------------
__global__ __launch_bounds__(512) void k_gemm_out(
    const unsigned short* __restrict__ Abf,
    const unsigned short* __restrict__ Wot,
    const float* __restrict__ bo,
    float* __restrict__ out)
{
    __shared__ unsigned short Al[2][128 * 32];
    __shared__ unsigned short Bl[2][128 * 32];

    const int t = threadIdx.x;
    const int lane = t & 63, w = t >> 6;          // 8 waves, 2x4
    const int lr = lane & 15, lg = lane >> 4;
    const int wr = w >> 2, wc = w & 3;

    const int m0 = blockIdx.x * 128;
    const int n0 = blockIdx.y * 128;

    const int srow = t >> 2;
    const int sc = (((t & 3) ^ ((srow >> 1) & 3))) * 8;
    const unsigned short* Ag = &Abf[(size_t)(m0 + srow) * HID_ + sc];
    const unsigned short* Bg = &Wot[(size_t)(n0 + srow) * HID_ + sc];
    char* dA = (char*)&Al[0][0] + w * 1024;
    char* dB = (char*)&Bl[0][0] + w * 1024;

    const int fx = (lr >> 1) & 3;
    int aoff[4], boff[2];
    #pragma unroll
    for (int i = 0; i < 4; ++i)
        aoff[i] = (wr * 64 + i * 16 + lr) * 32 + ((lg ^ fx) * 8);
    #pragma unroll
    for (int i = 0; i < 2; ++i)
        boff[i] = (wc * 32 + i * 16 + lr) * 32 + ((lg ^ fx) * 8);

    gload16(Ag, dA);
    gload16(Bg, dB);
    __syncthreads();

    f4 acc[4][2] = {};
    for (int kt = 0; kt < 16; ++kt) {
        const int cur = kt & 1;
        if (kt < 15) {
            const int ko = (kt + 1) * 32;
            const int bo_ = (cur ^ 1) * 8192;
            gload16(Ag + ko, dA + bo_);
            gload16(Bg + ko, dB + bo_);
        }
        bf8 af[4], bf_[2];
        #pragma unroll
        for (int i = 0; i < 4; ++i) af[i] = *(const bf8*)&Al[cur][aoff[i]];
        #pragma unroll
        for (int i = 0; i < 2; ++i) bf_[i] = *(const bf8*)&Bl[cur][boff[i]];
        #pragma unroll
        for (int mi = 0; mi < 4; ++mi)
            #pragma unroll
            for (int ni = 0; ni < 2; ++ni)
                acc[mi][ni] = MFMA16(af[mi], bf_[ni], acc[mi][ni]);
        __syncthreads();
    }

    #pragma unroll
    for (int mi = 0; mi < 4; ++mi)
    #pragma unroll
    for (int ni = 0; ni < 2; ++ni) {
        const int col = n0 + wc * 32 + ni * 16 + lr;
        const float bs = bo[col];
        const int row0 = m0 + wr * 64 + mi * 16 + lg * 4;
        #pragma unroll
        for (int r = 0; r < 4; ++r)
            out[(size_t)(row0 + r) * HID_ + col] = acc[mi][ni][r] + bs;
    }
}

// ---------------- flash attention: 4 waves x 32 q, mfma 32x32x16, deferred-PV
//   pipeline: {QK(t) || PV(t-1)} MFMA cluster, softmax overlaps; 4-buffer K/V ----------------
__global__ __launch_bounds__(256, 2) void k_flash(
    const unsigned short* __restrict__ Q, const unsigned short* __restrict__ K,
    const unsigned short* __restrict__ Vt,
    const float* __restrict__ rel_table, const float* __restrict__ maskadd,
    unsigned short* __restrict__ ctx)
{
    __shared__ unsigned short KV[4][8192];   // per buf: [0,4096) = K tile, [4096,8192) = V tile
    __shared__ float Tw[1216];               // bias window, rel in [-605,605], pre-clipped, *log2e
    __shared__ float maskc[S_];              // additive mask

    const int t = threadIdx.x;
    const int lane = t & 63, w = t >> 6;     // 4 waves
    const int q = lane & 31, hi = lane >> 5;

    // bijective XCD swizzle: each XCD owns 4 complete (b,h) pairs
    const int flat = blockIdx.x;             // 0..511
    const int idx = flat >> 3;
    const int bh = (flat & 7) * 4 + (idx >> 4);
    const int qb = idx & 15;
    const int b = bh >> 3, h = bh & 7;
    const int q0 = qb * 128;

    for (int i = t; i < 1216; i += 256) {
        int r = i - 606;
        r = r < -MAXREL ? -MAXREL : (r > MAXREL ? MAXREL : r);
        Tw[i] = rel_table[(r + MAXREL) * NH_ + h] * LOG2E;
    }
    {   // maskc: 2048 floats, vectorized
        const float4* src = (const float4*)(maskadd + b * S_);
        float4* dst = (float4*)maskc;
        for (int i = t; i < S_ / 4; i += 256) dst[i] = src[i];
    }
    const float TbLo = rel_table[h] * LOG2E;                    // rel = -512
    const float TbHi = rel_table[2 * MAXREL * NH_ + h] * LOG2E; // rel = +512

    const unsigned short* Kb = K + (size_t)bh * S_ * HD_;
    const unsigned short* Vb = Vt + (size_t)bh * HD_ * S_;

    const int myq = q0 + w * 32 + q;
    const int qw = q0 + w * 32;
    bf8 qf[4];   // B-frag: col=q, k(d)=16s+8hi+j
    #pragma unroll
    for (int s = 0; s < 4; ++s)
        qf[s] = *(const bf8*)&Q[((size_t)bh * S_ + myq) * HD_ + s * 16 + hi * 8];

    // staging: thread t -> rows t>>3 and t>>3+32, slot t&7; source col pre-swizzled
    const int srow = t >> 3, sslot = t & 7;
    const int sxor = (sslot ^ (srow & 7)) * 8;            // (srow+32)&7 == srow&7
    const size_t kb0 = (size_t)srow * HD_ + sxor;
    const size_t kb1 = (size_t)(srow + 32) * HD_ + sxor;
    const size_t vb0 = (size_t)srow * S_ + sxor;
    const size_t vb1 = (size_t)(srow + 32) * S_ + sxor;
    const int woff = w * 1024;                            // wave's linear LDS chunk (bytes)

    auto stage = [&](int kvt, int buf) {
        char* base = (char*)&KV[buf][0];
        const size_t ko = (size_t)kvt * 64 * HD_;
        const size_t vo = (size_t)kvt * 64;
        gload16(&Kb[kb0 + ko], base + woff);
        gload16(&Kb[kb1 + ko], base + 4096 + woff);
        gload16(&Vb[vb0 + vo], base + 8192 + woff);
        gload16(&Vb[vb1 + vo], base + 8192 + 4096 + woff);
    };

    f16f ca0 = {}, ca1 = {};       // ctx^T: col=q, d = {0,32} + (reg&3)+8*(reg>>2)+4hi
    float m_s = -INFINITY, lsum = 0.f;
    bf8 pfA, pfB, pfC, pfD;        // deferred P fragments (tile t-1)
    pfA = pfB = pfC = pfD = bf8{};

    // prologue: 2 tiles in flight
    stage(0, 0);
    stage(1, 1);
    asm volatile("s_waitcnt lgkmcnt(0)" ::: "memory");   // Tw/maskc ds_writes drained
    asm volatile("s_waitcnt vmcnt(4)" ::: "memory");     // buf0 ready (tile1 may remain)
    __builtin_amdgcn_s_barrier();
    __builtin_amdgcn_sched_barrier(0);

    const int xq = q & 7;
    // Tw index base: Tw[606 + rel], rel = key - myq; key = kv0(+32c) + 8m + 4hi + r
    const int jb0 = 606 - q0 - w * 32 - q + 4 * hi;       // + kv0 + 32c + 8m + r
    for (int ti = 0; ti < 32; ++ti) {
        const int kv0 = ti * 64;
        const int cur = ti & 3;

        // async-stage tile ti+2 into buf (ti+2)&3 — never clobbers t-1 (4 bufs)
        if (ti < 30) stage(ti + 2, (ti + 2) & 3);

        const unsigned short* Kt = &KV[cur][0];

        // ---- MFMA cluster: QK^T(t) || PV(t-1) — independent accumulators ----
        f16f sa0 = {}, sa1 = {};
        __builtin_amdgcn_s_setprio(1);
        #pragma unroll
        for (int s = 0; s < 4; ++s) {
            const int slot = ((2 * s + hi) ^ xq) * 8;
            bf8 k0 = *(const bf8*)&Kt[q * 64 + slot];
            bf8 k1 = *(const bf8*)&Kt[(q + 32) * 64 + slot];
            sa0 = MFMA32(k0, qf[s], sa0);
            sa1 = MFMA32(k1, qf[s], sa1);
        }
        if (ti > 0) {
            const unsigned short* Vp = &KV[(ti + 3) & 3][4096];   // buf of tile t-1
            #pragma unroll
            for (int s = 0; s < 4; ++s) {
                const int slot = ((2 * s + hi) ^ xq) * 8;
                bf8 v0 = *(const bf8*)&Vp[q * 64 + slot];
                bf8 v1 = *(const bf8*)&Vp[(q + 32) * 64 + slot];
                bf8 pf = (s == 0) ? pfA : (s == 1) ? pfB : (s == 2) ? pfC : pfD;
                ca0 = MFMA32(v0, pf, ca0);
                ca1 = MFMA32(v1, pf, ca1);
            }
        }
        __builtin_amdgcn_s_setprio(0);

        // ---- bias + mask + row max (4 parallel max accumulators) ----
        float t0 = -INFINITY, t1 = -INFINITY, t2 = -INFINITY, t3 = -INFINITY;
        {
            const bool ulo = (kv0 + 31 - qw <= -MAXREL);
            const bool uhi = (kv0 - (qw + 31) >= MAXREL);
            if (ulo || uhi) {
                const float bc = ulo ? TbLo : TbHi;
                #pragma unroll
                for (int m = 0; m < 4; ++m) {
                    float4 mk = *(const float4*)&maskc[kv0 + m * 8 + hi * 4];
                    float s0 = sa0[4 * m + 0] + bc + mk.x;  sa0[4 * m + 0] = s0;  t0 = fmaxf(t0, s0);
                    float s1 = sa0[4 * m + 1] + bc + mk.y;  sa0[4 * m + 1] = s1;  t1 = fmaxf(t1, s1);
                    float s2 = sa0[4 * m + 2] + bc + mk.z;  sa0[4 * m + 2] = s2;  t2 = fmaxf(t2, s2);
                    float s3 = sa0[4 * m + 3] + bc + mk.w;  sa0[4 * m + 3] = s3;  t3 = fmaxf(t3, s3);
                }
            } else {
                #pragma unroll
                for (int m = 0; m < 4; ++m) {
                    float4 mk = *(const float4*)&maskc[kv0 + m * 8 + hi * 4];
                    const int jb = jb0 + kv0 + m * 8;
                    float s0 = sa0[4 * m + 0] + Tw[jb + 0] + mk.x;  sa0[4 * m + 0] = s0;  t0 = fmaxf(t0, s0);
                    float s1 = sa0[4 * m + 1] + Tw[jb + 1] + mk.y;  sa0[4 * m + 1] = s1;  t1 = fmaxf(t1, s1);
                    float s2 = sa0[4 * m + 2] + Tw[jb + 2] + mk.z;  sa0[4 * m + 2] = s2;  t2 = fmaxf(t2, s2);
                    float s3 = sa0[4 * m + 3] + Tw[jb + 3] + mk.w;  sa0[4 * m + 3] = s3;  t3 = fmaxf(t3, s3);
                }
            }
            const int kvh = kv0 + 32;
            const bool ulo1 = (kvh + 31 - qw <= -MAXREL);
            const bool uhi1 = (kvh - (qw + 31) >= MAXREL);
            if (ulo1 || uhi1) {
                const float bc = ulo1 ? TbLo : TbHi;
                #pragma unroll
                for (int m = 0; m < 4; ++m) {
                    float4 mk = *(const float4*)&maskc[kvh + m * 8 + hi * 4];
                    float s0 = sa1[4 * m + 0] + bc + mk.x;  sa1[4 * m + 0] = s0;  t0 = fmaxf(t0, s0);
                    float s1 = sa1[4 * m + 1] + bc + mk.y;  sa1[4 * m + 1] = s1;  t1 = fmaxf(t1, s1);
                    float s2 = sa1[4 * m + 2] + bc + mk.z;  sa1[4 * m + 2] = s2;  t2 = fmaxf(t2, s2);
                    float s3 = sa1[4 * m + 3] + bc + mk.w;  sa1[4 * m + 3] = s3;  t3 = fmaxf(t3, s3);
                }
            } else {
                #pragma unroll
                for (int m = 0; m < 4; ++m) {
                    float4 mk = *(const float4*)&maskc[kvh + m * 8 + hi * 4];
                    const int jb = jb0 + kvh + m * 8;
                    float s0 = sa1[4 * m + 0] + Tw[jb + 0] + mk.x;  sa1[4 * m + 0] = s0;  t0 = fmaxf(t0, s0);
                    float s1 = sa1[4 * m + 1] + Tw[jb + 1] + mk.y;  sa1[4 * m + 1] = s1;  t1 = fmaxf(t1, s1);
                    float s2 = sa1[4 * m + 2] + Tw[jb + 2] + mk.z;  sa1[4 * m + 2] = s2;  t2 = fmaxf(t2, s2);
                    float s3 = sa1[4 * m + 3] + Tw[jb + 3] + mk.w;  sa1[4 * m + 3] = s3;  t3 = fmaxf(t3, s3);
                }
            }
        }
        float tmaxl = fmaxf(fmaxf(t0, t1), fmaxf(t2, t3));
        const float tmax = fmaxf(tmaxl, __shfl_xor(tmaxl, 32));   // row = lanes q, q+32

        // ---- speculative exp with current m_s (defer-max common case) ----
        float ptile = 0.f;
        unsigned int pkA[8], pkB[8];
        #pragma unroll
        for (int m = 0; m < 4; ++m) {
            float a0 = ex2(sa0[4 * m + 0] - m_s), a1 = ex2(sa0[4 * m + 1] - m_s);
            float a2 = ex2(sa0[4 * m + 2] - m_s), a3 = ex2(sa0[4 * m + 3] - m_s);
            float b0 = ex2(sa1[4 * m + 0] - m_s), b1 = ex2(sa1[4 * m + 1] - m_s);
            float b2 = ex2(sa1[4 * m + 2] - m_s), b3 = ex2(sa1[4 * m + 3] - m_s);
            ptile += ((a0 + a1) + (a2 + a3)) + ((b0 + b1) + (b2 + b3));
            asm("v_cvt_pk_bf16_f32 %0, %1, %2" : "=v"(pkA[2 * m])     : "v"(a0), "v"(a1));
            asm("v_cvt_pk_bf16_f32 %0, %1, %2" : "=v"(pkA[2 * m + 1]) : "v"(a2), "v"(a3));
            asm("v_cvt_pk_bf16_f32 %0, %1, %2" : "=v"(pkB[2 * m])     : "v"(b0), "v"(b1));
            asm("v_cvt_pk_bf16_f32 %0, %1, %2" : "=v"(pkB[2 * m + 1]) : "v"(b2), "v"(b3));
        }
        if (!__all(tmax <= m_s + 8.0f)) {     // rare: rescale + recompute
            const float mnew = fmaxf(m_s, tmax);
            const float fac = ex2(m_s - mnew);
            lsum *= fac;
            ca0 *= fac;       // includes PV through t-1 at old scale -> consistent
            ca1 *= fac;
            ptile = 0.f;
            #pragma unroll
            for (int m = 0; m < 4; ++m) {
                float a0 = ex2(sa0[4 * m + 0] - mnew), a1 = ex2(sa0[4 * m + 1] - mnew);
                float a2 = ex2(sa0[4 * m + 2] - mnew), a3 = ex2(sa0[4 * m + 3] - mnew);
                float b0 = ex2(sa1[4 * m + 0] - mnew), b1 = ex2(sa1[4 * m + 1] - mnew);
                float b2 = ex2(sa1[4 * m + 2] - mnew), b3 = ex2(sa1[4 * m + 3] - mnew);
                ptile += ((a0 + a1) + (a2 + a3)) + ((b0 + b1) + (b2 + b3));
                asm("v_cvt_pk_bf16_f32 %0, %1, %2" : "=v"(pkA[2 * m])     : "v"(a0), "v"(a1));
                asm("v_cvt_pk_bf16_f32 %0, %1, %2" : "=v"(pkA[2 * m + 1]) : "v"(a2), "v"(a3));
                asm("v_cvt_pk_bf16_f32 %0, %1, %2" : "=v"(pkB[2 * m])     : "v"(b0), "v"(b1));
                asm("v_cvt_pk_bf16_f32 %0, %1, %2" : "=v"(pkB[2 * m + 1]) : "v"(b2), "v"(b3));
            }
            m_s = mnew;
        }
        lsum += ptile;

        // ---- P B-frags via permlane32_swap (held for next body's PV) ----
        {
            unsigned c0 = pkA[0], c2 = pkA[2], c1 = pkA[1], c3 = pkA[3];
            asm("v_permlane32_swap_b32 %0, %1" : "+v"(c0), "+v"(c2));
            asm("v_permlane32_swap_b32 %0, %1" : "+v"(c1), "+v"(c3));
            pfA = mkbf8(c0, c1, c2, c3);
        }
        {
            unsigned c0 = pkA[4], c2 = pkA[6], c1 = pkA[5], c3 = pkA[7];
            asm("v_permlane32_swap_b32 %0, %1" : "+v"(c0), "+v"(c2));
            asm("v_permlane32_swap_b32 %0, %1" : "+v"(c1), "+v"(c3));
            pfB = mkbf8(c0, c1, c2, c3);
        }
        {
            unsigned c0 = pkB[0], c2 = pkB[2], c1 = pkB[1], c3 = pkB[3];
            asm("v_permlane32_swap_b32 %0, %1" : "+v"(c0), "+v"(c2));
            asm("v_permlane32_swap_b32 %0, %1" : "+v"(c1), "+v"(c3));
            pfC = mkbf8(c0, c1, c2, c3);
        }
        {
            unsigned c0 = pkB[4], c2 = pkB[6], c1 = pkB[5], c3 = pkB[7];
            asm("v_permlane32_swap_b32 %0, %1" : "+v"(c0), "+v"(c2));
            asm("v_permlane32_swap_b32 %0, %1" : "+v"(c1), "+v"(c3));
            pfD = mkbf8(c0, c1, c2, c3);
        }

        // ---- counted-vmcnt barrier: next tile's buffer ready, deeper loads in flight ----
        if (ti < 31) {
            if (ti < 30) asm volatile("s_waitcnt vmcnt(4)" ::: "memory");
            else         asm volatile("s_waitcnt vmcnt(0)" ::: "memory");
            __builtin_amdgcn_s_barrier();
            __builtin_amdgcn_sched_barrier(0);
        }
    }

    // ---- final deferred PV (tile 31, buf 3) ----
    {
        const unsigned short* Vp = &KV[3][4096];
        __builtin_amdgcn_s_setprio(1);
        #pragma unroll
        for (int s = 0; s < 4; ++s) {
            const int slot = ((2 * s + hi) ^ xq) * 8;
            bf8 v0 = *(const bf8*)&Vp[q * 64 + slot];
            bf8 v1 = *(const bf8*)&Vp[(q + 32) * 64 + slot];
            bf8 pf = (s == 0) ? pfA : (s == 1) ? pfB : (s == 2) ? pfC : pfD;
            ca0 = MFMA32(v0, pf, ca0);
            ca1 = MFMA32(v1, pf, ca1);
        }
        __builtin_amdgcn_s_setprio(0);
    }

    // ---- epilogue: reduce l across row halves, divide, write ----
    lsum += __shfl_xor(lsum, 32);
    const float inv = 1.0f / lsum;
    unsigned short* cg = &ctx[(size_t)(b * S_ + myq) * HID_ + h * HD_];
    #pragma unroll
    for (int m = 0; m < 4; ++m) {
        ushort4 o0;
        o0.x = f2bf(ca0[4 * m + 0] * inv);
        o0.y = f2bf(ca0[4 * m + 1] * inv);
        o0.z = f2bf(ca0[4 * m + 2] * inv);
        o0.w = f2bf(ca0[4 * m + 3] * inv);
        *(ushort4*)&cg[m * 8 + hi * 4] = o0;
        ushort4 o1;
        o1.x = f2bf(ca1[4 * m + 0] * inv);
        o1.y = f2bf(ca1[4 * m + 1] * inv);
        o1.z = f2bf(ca1[4 * m + 2] * inv);
        o1.w = f2bf(ca1[4 * m + 3] * inv);
        *(ushort4*)&cg[32 + m * 8 + hi * 4] = o1;
    }
}

// ---------------- launcher ----------------
extern "C" void kernel_launch(void* const* d_in, const int* in_sizes, int n_in,
                              void* d_out, int out_size, void* d_ws, size_t ws_size,
                              hipStream_t stream) {
    const float* hs  = (const float*)d_in[0];
    const float* msk = (const float*)d_in[1];
    const float* Wq  = (const float*)d_in[2];
    const float* bq  = (const float*)d_in[3];
    const float* Wk  = (const float*)d_in[4];
    const float* bk  = (const float*)d_in[5];
    const float* Wv  = (const float*)d_in[6];
    const float* bv  = (const float*)d_in[7];
    const float* Wo  = (const float*)d_in[8];
    const float* bo  = (const float*)d_in[9];
    const float* rel = (const float*)d_in[10];
    float* out = (float*)d_out;

    char* ws = (char*)d_ws;
    unsigned short* hsb = (unsigned short*)ws; ws += (size_t)M_ * HID_ * 2;
    unsigned short* Wqt = (unsigned short*)ws; ws += (size_t)HID_ * HID_ * 2;
    unsigned short* Wkt = (unsigned short*)ws; ws += (size_t)HID_ * HID_ * 2;
    unsigned short* Wvt = (unsigned short*)ws; ws += (size_t)HID_ * HID_ * 2;
    unsigned short* Wot = (unsigned short*)ws; ws += (size_t)HID_ * HID_ * 2;
    unsigned short* Qb  = (unsigned short*)ws; ws += (size_t)M_ * HID_ * 2;
    unsigned short* Kb  = (unsigned short*)ws; ws += (size_t)M_ * HID_ * 2;
    unsigned short* Vtb = (unsigned short*)ws; ws += (size_t)M_ * HID_ * 2;
    unsigned short* ctxb= (unsigned short*)ws; ws += (size_t)M_ * HID_ * 2;
    float* maskadd      = (float*)ws;          ws += (size_t)M_ * 4;

    k_cast_hs<<<(M_ * HID_ / 4 + 255) / 256, 256, 0, stream>>>(hs, hsb, M_ * HID_ / 4);
    k_prep_mask<<<(M_ + 255) / 256, 256, 0, stream>>>(msk, maskadd);
    k_transpose_w4<<<dim3(16, 16, 4), 256, 0, stream>>>(Wq, Wk, Wv, Wo, Wqt, Wkt, Wvt, Wot);
    k_gemm_qkv<<<dim3(64, 12), 256, 0, stream>>>(
        hsb, Wqt, Wkt, Wvt, bq, bk, bv, Qb, Kb, Vtb);
    k_flash<<<512, 256, 0, stream>>>(Qb, Kb, Vtb, rel, maskadd, ctxb);
    k_gemm_out<<<dim3(64, 4), 512, 0, stream>>>(ctxb, Wot, bo, out);
}

// Round 13
// 110.513 us; speedup vs baseline: 1.0168x; 1.0168x over previous
//
#include <hip/hip_runtime.h>
#include <hip/hip_bf16.h>

#define B_    4
#define S_    2048
#define HID_  512
#define NH_   8
#define HD_   64
#define MAXREL 512
#define M_    (B_ * S_)   // 8192 tokens

#define LOG2E 1.44269504f
#define SCALE_Q (0.125f * LOG2E)   // folded into Q at projection time

typedef __attribute__((ext_vector_type(8))) short bf8;            // 8 bf16 (MFMA A/B frag)
typedef __attribute__((ext_vector_type(4))) float f4;             // 16x16 C/D frag
typedef __attribute__((ext_vector_type(16))) float f16f;          // 32x32 C/D frag

static __device__ __forceinline__ unsigned short f2bf(float f) {
    union { float f; unsigned int u; } v; v.f = f;
    unsigned int u = v.u;
    unsigned int r = (u + 0x7FFFu + ((u >> 16) & 1u)) >> 16;   // round-nearest-even
    return (unsigned short)r;
}

static __device__ __forceinline__ float ex2(float x) {   // raw v_exp_f32 (base-2)
    float r; asm("v_exp_f32 %0, %1" : "=v"(r) : "v"(x)); return r;
}

// async global->LDS, 16B per lane; dest = wave-uniform base + lane*16 (linear)
static __device__ __forceinline__ void gload16(const void* g, void* l) {
    __builtin_amdgcn_global_load_lds(
        (const __attribute__((address_space(1))) unsigned int*)g,
        (__attribute__((address_space(3))) unsigned int*)l, 16, 0, 0);
}

static __device__ __forceinline__ bf8 mkbf8(unsigned a, unsigned b, unsigned c, unsigned d) {
    uint4 u = make_uint4(a, b, c, d);
    return *(bf8*)&u;
}

#define MFMA16(a, b, c) __builtin_amdgcn_mfma_f32_16x16x32_bf16((a), (b), (c), 0, 0, 0)
#define MFMA32(a, b, c) __builtin_amdgcn_mfma_f32_32x32x16_bf16((a), (b), (c), 0, 0, 0)

// ---------------- cast hidden_states fp32 -> bf16 ----------------
__global__ void k_cast_hs(const float* __restrict__ src, unsigned short* __restrict__ dst, int n4) {
    int i = blockIdx.x * blockDim.x + threadIdx.x;
    if (i >= n4) return;
    float4 v = ((const float4*)src)[i];
    ushort4 o;
    o.x = f2bf(v.x); o.y = f2bf(v.y); o.z = f2bf(v.z); o.w = f2bf(v.w);
    ((ushort4*)dst)[i] = o;
}

// ---------------- mask -> additive form (0 attend / -3e38 masked) ----------------
__global__ void k_prep_mask(const float* __restrict__ mask, float* __restrict__ maskadd) {
    int i = blockIdx.x * blockDim.x + threadIdx.x;
    if (i < M_) maskadd[i] = (1.0f - mask[i]) * -3.0e38f;
}

// ---------------- transpose + cast 4 weights (LDS 32x32 tiles) ----------------
__global__ void k_transpose_w4(const float* __restrict__ W0, const float* __restrict__ W1,
                               const float* __restrict__ W2, const float* __restrict__ W3,
                               unsigned short* __restrict__ T0, unsigned short* __restrict__ T1,
                               unsigned short* __restrict__ T2, unsigned short* __restrict__ T3) {
    __shared__ float tile[32][33];
    const int z = blockIdx.z;
    const float* W = (z == 0) ? W0 : (z == 1) ? W1 : (z == 2) ? W2 : W3;
    unsigned short* T = (z == 0) ? T0 : (z == 1) ? T1 : (z == 2) ? T2 : T3;
    const int tx = threadIdx.x & 31, ty = threadIdx.x >> 5;   // 256 thr
    const int n0 = blockIdx.x * 32, k0 = blockIdx.y * 32;
    #pragma unroll
    for (int i = 0; i < 4; ++i)
        tile[ty + i * 8][tx] = W[(size_t)(k0 + ty + i * 8) * HID_ + n0 + tx];
    __syncthreads();
    #pragma unroll
    for (int i = 0; i < 4; ++i)
        T[(size_t)(n0 + ty + i * 8) * HID_ + k0 + tx] = f2bf(tile[tx][ty + i * 8]);
}

// ---------------- fused QKV GEMM: 128x128 tile, dbuf LDS via global_load_lds ----------------
__global__ __launch_bounds__(256, 3) void k_gemm_qkv(
    const unsigned short* __restrict__ Abf,
    const unsigned short* __restrict__ Wqt, const unsigned short* __restrict__ Wkt,
    const unsigned short* __restrict__ Wvt,
    const float* __restrict__ bq, const float* __restrict__ bk, const float* __restrict__ bv,
    unsigned short* __restrict__ Q, unsigned short* __restrict__ K, unsigned short* __restrict__ Vt)
{
    __shared__ unsigned short Al[2][128 * 32];
    __shared__ unsigned short Bl[2][128 * 32];

    const int t = threadIdx.x;
    const int lane = t & 63, w = t >> 6;
    const int lr = lane & 15, lg = lane >> 4;
    const int wr = w >> 1, wc = w & 1;

    const int m0 = blockIdx.x * 128;
    const int ng = blockIdx.y * 128;
    const int z = ng >> 9;
    const int n0 = ng & 511;
    const unsigned short* Wt = (z == 0) ? Wqt : ((z == 1) ? Wkt : Wvt);
    const float* bias = (z == 0) ? bq : ((z == 1) ? bk : bv);
    const float osc = (z == 0) ? SCALE_Q : 1.0f;

    const int srow = t >> 2;
    const int sc = (((t & 3) ^ ((srow >> 1) & 3))) * 8;     // swizzled source col
    const unsigned short* Ag0 = &Abf[(size_t)(m0 + srow) * HID_ + sc];
    const unsigned short* Ag1 = &Abf[(size_t)(m0 + 64 + srow) * HID_ + sc];
    const unsigned short* Bg0 = &Wt[(size_t)(n0 + srow) * HID_ + sc];
    const unsigned short* Bg1 = &Wt[(size_t)(n0 + 64 + srow) * HID_ + sc];
    char* dA0 = (char*)&Al[0][0] + w * 1024;
    char* dB0 = (char*)&Bl[0][0] + w * 1024;

    const int fx = (lr >> 1) & 3;
    int aoff[4], boff[4];
    #pragma unroll
    for (int i = 0; i < 4; ++i) {
        aoff[i] = (wr * 64 + i * 16 + lr) * 32 + ((lg ^ fx) * 8);
        boff[i] = (wc * 64 + i * 16 + lr) * 32 + ((lg ^ fx) * 8);
    }

    gload16(Ag0, dA0);
    gload16(Ag1, dA0 + 4096);
    gload16(Bg0, dB0);
    gload16(Bg1, dB0 + 4096);
    __syncthreads();

    f4 acc[4][4] = {};
    for (int kt = 0; kt < 16; ++kt) {
        const int cur = kt & 1;
        if (kt < 15) {
            const int ko = (kt + 1) * 32;
            const int bo = (cur ^ 1) * 8192;
            gload16(Ag0 + ko, dA0 + bo);
            gload16(Ag1 + ko, dA0 + bo + 4096);
            gload16(Bg0 + ko, dB0 + bo);
            gload16(Bg1 + ko, dB0 + bo + 4096);
        }
        bf8 af[4], bf_[4];
        #pragma unroll
        for (int i = 0; i < 4; ++i) {
            af[i]  = *(const bf8*)&Al[cur][aoff[i]];
            bf_[i] = *(const bf8*)&Bl[cur][boff[i]];
        }
        #pragma unroll
        for (int mi = 0; mi < 4; ++mi)
            #pragma unroll
            for (int ni = 0; ni < 4; ++ni)
                acc[mi][ni] = MFMA16(af[mi], bf_[ni], acc[mi][ni]);
        __syncthreads();
    }

    #pragma unroll
    for (int mi = 0; mi < 4; ++mi)
    #pragma unroll
    for (int ni = 0; ni < 4; ++ni) {
        const int col = n0 + wc * 64 + ni * 16 + lr;
        const int h = col >> 6, d = col & 63;
        const float bs = bias[col];
        const int row0 = m0 + wr * 64 + mi * 16 + lg * 4;
        const int b = row0 >> 11, s0 = row0 & 2047;
        if (z == 2) {
            ushort4 o;
            o.x = f2bf(acc[mi][ni][0] + bs);
            o.y = f2bf(acc[mi][ni][1] + bs);
            o.z = f2bf(acc[mi][ni][2] + bs);
            o.w = f2bf(acc[mi][ni][3] + bs);
            *(ushort4*)&Vt[(((size_t)(b * NH_ + h)) * HD_ + d) * S_ + s0] = o;
        } else {
            unsigned short* dst = (z == 0) ? Q : K;
            #pragma unroll
            for (int r = 0; r < 4; ++r) {
                float v = (acc[mi][ni][r] + bs) * osc;
                dst[(((size_t)(b * NH_ + h)) * S_ + s0 + r) * HD_ + d] = f2bf(v);
            }
        }
    }
}

// ---------------- output projection GEMM: 128x128 tile, 512 threads ----------------
__global__ __launch_bounds__(512) void k_gemm_out(
    const unsigned short* __restrict__ Abf,
    const unsigned short* __restrict__ Wot,
    const float* __restrict__ bo,
    float* __restrict__ out)
{
    __shared__ unsigned short Al[2][128 * 32];
    __shared__ unsigned short Bl[2][128 * 32];

    const int t = threadIdx.x;
    const int lane = t & 63, w = t >> 6;          // 8 waves, 2x4
    const int lr = lane & 15, lg = lane >> 4;
    const int wr = w >> 2, wc = w & 3;

    const int m0 = blockIdx.x * 128;
    const int n0 = blockIdx.y * 128;

    const int srow = t >> 2;
    const int sc = (((t & 3) ^ ((srow >> 1) & 3))) * 8;
    const unsigned short* Ag = &Abf[(size_t)(m0 + srow) * HID_ + sc];
    const unsigned short* Bg = &Wot[(size_t)(n0 + srow) * HID_ + sc];
    char* dA = (char*)&Al[0][0] + w * 1024;
    char* dB = (char*)&Bl[0][0] + w * 1024;

    const int fx = (lr >> 1) & 3;
    int aoff[4], boff[2];
    #pragma unroll
    for (int i = 0; i < 4; ++i)
        aoff[i] = (wr * 64 + i * 16 + lr) * 32 + ((lg ^ fx) * 8);
    #pragma unroll
    for (int i = 0; i < 2; ++i)
        boff[i] = (wc * 32 + i * 16 + lr) * 32 + ((lg ^ fx) * 8);

    gload16(Ag, dA);
    gload16(Bg, dB);
    __syncthreads();

    f4 acc[4][2] = {};
    for (int kt = 0; kt < 16; ++kt) {
        const int cur = kt & 1;
        if (kt < 15) {
            const int ko = (kt + 1) * 32;
            const int bo_ = (cur ^ 1) * 8192;
            gload16(Ag + ko, dA + bo_);
            gload16(Bg + ko, dB + bo_);
        }
        bf8 af[4], bf_[2];
        #pragma unroll
        for (int i = 0; i < 4; ++i) af[i] = *(const bf8*)&Al[cur][aoff[i]];
        #pragma unroll
        for (int i = 0; i < 2; ++i) bf_[i] = *(const bf8*)&Bl[cur][boff[i]];
        #pragma unroll
        for (int mi = 0; mi < 4; ++mi)
            #pragma unroll
            for (int ni = 0; ni < 2; ++ni)
                acc[mi][ni] = MFMA16(af[mi], bf_[ni], acc[mi][ni]);
        __syncthreads();
    }

    #pragma unroll
    for (int mi = 0; mi < 4; ++mi)
    #pragma unroll
    for (int ni = 0; ni < 2; ++ni) {
        const int col = n0 + wc * 32 + ni * 16 + lr;
        const float bs = bo[col];
        const int row0 = m0 + wr * 64 + mi * 16 + lg * 4;
        #pragma unroll
        for (int r = 0; r < 4; ++r)
            out[(size_t)(row0 + r) * HID_ + col] = acc[mi][ni][r] + bs;
    }
}

// ---------------- flash attention: 8 waves = 4 q-groups x 2 kv-halves, mfma 32x32x16.
//   Wave (g, kvh) handles q rows [q0+32g, +32) x keys [kv0+32*kvh, +32) of each shared
//   tile -> 4096 waves (4/SIMD). Shared 3-buf K/V ring (counted vmcnt), permlane P,
//   speculative exp + defer-max; pair-merge (m,l,ctx) through LDS at the end. ----------------
__global__ __launch_bounds__(512, 4) void k_flash(
    const unsigned short* __restrict__ Q, const unsigned short* __restrict__ K,
    const unsigned short* __restrict__ Vt,
    const float* __restrict__ rel_table, const float* __restrict__ maskadd,
    unsigned short* __restrict__ ctx)
{
    __shared__ unsigned short KV[3][8192];   // per buf: [0,4096) ushorts K, [4096,8192) V
    __shared__ float Tw[1216];               // bias window, rel in [-605,605], pre-clipped, *log2e
    __shared__ float maskc[S_];              // additive mask

    const int t = threadIdx.x;
    const int lane = t & 63, w = t >> 6;     // 8 waves
    const int q = lane & 31, hi = lane >> 5;
    const int g = w & 3, kvh = w >> 2;       // q-group, kv-half

    // bijective XCD swizzle: each XCD owns 4 complete (b,h) pairs
    const int flat = blockIdx.x;             // 0..511
    const int idx = flat >> 3;
    const int bh = (flat & 7) * 4 + (idx >> 4);
    const int qb = idx & 15;
    const int b = bh >> 3, h = bh & 7;
    const int q0 = qb * 128;

    for (int i = t; i < 1216; i += 512) {
        int r = i - 606;
        r = r < -MAXREL ? -MAXREL : (r > MAXREL ? MAXREL : r);
        Tw[i] = rel_table[(r + MAXREL) * NH_ + h] * LOG2E;
    }
    {
        const float4* src = (const float4*)(maskadd + b * S_);
        float4* dst = (float4*)maskc;
        for (int i = t; i < S_ / 4; i += 512) dst[i] = src[i];
    }
    const float TbLo = rel_table[h] * LOG2E;                    // rel = -512
    const float TbHi = rel_table[2 * MAXREL * NH_ + h] * LOG2E; // rel = +512

    const unsigned short* Kb = K + (size_t)bh * S_ * HD_;
    const unsigned short* Vb = Vt + (size_t)bh * HD_ * S_;

    const int myq = q0 + g * 32 + q;
    const int qw = q0 + g * 32;
    bf8 qf[4];   // B-frag: col=q, k(d)=16s+8hi+j
    #pragma unroll
    for (int s = 0; s < 4; ++s)
        qf[s] = *(const bf8*)&Q[((size_t)bh * S_ + myq) * HD_ + s * 16 + hi * 8];

    // staging (512 thr): thread t -> row t>>3 (0..63), slot t&7; source col pre-swizzled
    const int srow = t >> 3, sslot = t & 7;
    const int sxor = (sslot ^ (srow & 7)) * 8;
    const size_t kb0 = (size_t)srow * HD_ + sxor;
    const size_t vb0 = (size_t)srow * S_ + sxor;
    const int woff = w * 1024;               // wave's linear 1KB chunk (8 rows x 128B)

    auto stage = [&](int kvt, int buf) {
        char* base = (char*)&KV[buf][0];
        gload16(&Kb[kb0 + (size_t)kvt * 64 * HD_], base + woff);
        gload16(&Vb[vb0 + (size_t)kvt * 64], base + 8192 + woff);
    };

    f16f ca0 = {}, ca1 = {};       // ctx^T partial: col=q, d = {0,32} + (reg&3)+8*(reg>>2)+4hi
    float m_s = -INFINITY, lsum = 0.f;

    // prologue: 2 tiles in flight (2 loads/wave each)
    stage(0, 0);
    stage(1, 1);
    asm volatile("s_waitcnt lgkmcnt(0)" ::: "memory");   // Tw/maskc ds_writes drained
    asm volatile("s_waitcnt vmcnt(2)" ::: "memory");     // buf0 ready
    __builtin_amdgcn_s_barrier();
    __builtin_amdgcn_sched_barrier(0);

    const int xq = q & 7;
    // Tw index: 606 + key - myq; key = kv0 + 32*kvh + 8m + 4hi + r
    const int jb0 = 606 + 32 * kvh + 4 * hi - q0 - g * 32 - q;   // + kv0 + 8m + r
    for (int ti = 0; ti < 32; ++ti) {
        const int kv0 = ti * 64;
        const int cur = ti % 3;
        const int kvs = kv0 + 32 * kvh;      // this wave's 32-key window

        if (ti < 30) stage(ti + 2, (ti + 2) % 3);

        const unsigned short* Kt  = &KV[cur][0];
        const unsigned short* Vtl = &KV[cur][4096];

        // ---- QK^T (swapped): C[key_local][q], this wave's 32 keys ----
        f16f sa = {};
        __builtin_amdgcn_s_setprio(1);
        #pragma unroll
        for (int s = 0; s < 4; ++s) {
            bf8 kf = *(const bf8*)&Kt[(32 * kvh + q) * 64 + (((2 * s + hi) ^ xq) * 8)];
            sa = MFMA32(kf, qf[s], sa);
        }
        __builtin_amdgcn_s_setprio(0);

        // ---- bias + mask + row max (4 parallel max accumulators) ----
        float t0 = -INFINITY, t1 = -INFINITY, t2 = -INFINITY, t3 = -INFINITY;
        {
            const bool ulo = (kvs + 31 - qw <= -MAXREL);
            const bool uhi = (kvs - (qw + 31) >= MAXREL);
            if (ulo || uhi) {
                const float bc = ulo ? TbLo : TbHi;
                #pragma unroll
                for (int m = 0; m < 4; ++m) {
                    float4 mk = *(const float4*)&maskc[kvs + m * 8 + hi * 4];
                    float s0 = sa[4 * m + 0] + bc + mk.x;  sa[4 * m + 0] = s0;  t0 = fmaxf(t0, s0);
                    float s1 = sa[4 * m + 1] + bc + mk.y;  sa[4 * m + 1] = s1;  t1 = fmaxf(t1, s1);
                    float s2 = sa[4 * m + 2] + bc + mk.z;  sa[4 * m + 2] = s2;  t2 = fmaxf(t2, s2);
                    float s3 = sa[4 * m + 3] + bc + mk.w;  sa[4 * m + 3] = s3;  t3 = fmaxf(t3, s3);
                }
            } else {
                #pragma unroll
                for (int m = 0; m < 4; ++m) {
                    float4 mk = *(const float4*)&maskc[kvs + m * 8 + hi * 4];
                    const int jb = jb0 + kv0 + m * 8;
                    float s0 = sa[4 * m + 0] + Tw[jb + 0] + mk.x;  sa[4 * m + 0] = s0;  t0 = fmaxf(t0, s0);
                    float s1 = sa[4 * m + 1] + Tw[jb + 1] + mk.y;  sa[4 * m + 1] = s1;  t1 = fmaxf(t1, s1);
                    float s2 = sa[4 * m + 2] + Tw[jb + 2] + mk.z;  sa[4 * m + 2] = s2;  t2 = fmaxf(t2, s2);
                    float s3 = sa[4 * m + 3] + Tw[jb + 3] + mk.w;  sa[4 * m + 3] = s3;  t3 = fmaxf(t3, s3);
                }
            }
        }
        float tmaxl = fmaxf(fmaxf(t0, t1), fmaxf(t2, t3));
        const float tmax = fmaxf(tmaxl, __shfl_xor(tmaxl, 32));   // row = lanes q, q+32

        // ---- speculative exp with current m_s (defer-max common case) ----
        float ptile = 0.f;
        unsigned int pk[8];
        #pragma unroll
        for (int m = 0; m < 4; ++m) {
            float a0 = ex2(sa[4 * m + 0] - m_s), a1 = ex2(sa[4 * m + 1] - m_s);
            float a2 = ex2(sa[4 * m + 2] - m_s), a3 = ex2(sa[4 * m + 3] - m_s);
            ptile += (a0 + a1) + (a2 + a3);
            asm("v_cvt_pk_bf16_f32 %0, %1, %2" : "=v"(pk[2 * m])     : "v"(a0), "v"(a1));
            asm("v_cvt_pk_bf16_f32 %0, %1, %2" : "=v"(pk[2 * m + 1]) : "v"(a2), "v"(a3));
        }
        if (!__all(tmax <= m_s + 8.0f)) {     // rare: rescale + recompute
            const float mnew = fmaxf(m_s, tmax);
            const float fac = ex2(m_s - mnew);
            lsum *= fac;
            ca0 *= fac;
            ca1 *= fac;
            ptile = 0.f;
            #pragma unroll
            for (int m = 0; m < 4; ++m) {
                float a0 = ex2(sa[4 * m + 0] - mnew), a1 = ex2(sa[4 * m + 1] - mnew);
                float a2 = ex2(sa[4 * m + 2] - mnew), a3 = ex2(sa[4 * m + 3] - mnew);
                ptile += (a0 + a1) + (a2 + a3);
                asm("v_cvt_pk_bf16_f32 %0, %1, %2" : "=v"(pk[2 * m])     : "v"(a0), "v"(a1));
                asm("v_cvt_pk_bf16_f32 %0, %1, %2" : "=v"(pk[2 * m + 1]) : "v"(a2), "v"(a3));
            }
            m_s = mnew;
        }
        lsum += ptile;

        // ---- P B-frags via permlane32_swap (R9's verified recipe, kv-local [0,32)) ----
        bf8 pf0, pf1;
        {
            unsigned c0 = pk[0], c2 = pk[2], c1 = pk[1], c3 = pk[3];
            asm("v_permlane32_swap_b32 %0, %1" : "+v"(c0), "+v"(c2));
            asm("v_permlane32_swap_b32 %0, %1" : "+v"(c1), "+v"(c3));
            pf0 = mkbf8(c0, c1, c2, c3);
        }
        {
            unsigned c0 = pk[4], c2 = pk[6], c1 = pk[5], c3 = pk[7];
            asm("v_permlane32_swap_b32 %0, %1" : "+v"(c0), "+v"(c2));
            asm("v_permlane32_swap_b32 %0, %1" : "+v"(c1), "+v"(c3));
            pf1 = mkbf8(c0, c1, c2, c3);
        }

        // ---- PV (swapped): C[d][q] += mfma32(V^T frag, P frag), kv = this half ----
        __builtin_amdgcn_s_setprio(1);
        #pragma unroll
        for (int s = 0; s < 2; ++s) {
            const int slot = ((4 * kvh + 2 * s + hi) ^ xq) * 8;
            bf8 v0 = *(const bf8*)&Vtl[q * 64 + slot];
            bf8 v1 = *(const bf8*)&Vtl[(q + 32) * 64 + slot];
            bf8 pf = (s == 0) ? pf0 : pf1;
            ca0 = MFMA32(v0, pf, ca0);
            ca1 = MFMA32(v1, pf, ca1);
        }
        __builtin_amdgcn_s_setprio(0);

        // ---- counted-vmcnt barrier ----
        if (ti < 31) {
            if (ti < 30) asm volatile("s_waitcnt vmcnt(2)" ::: "memory");
            else         asm volatile("s_waitcnt vmcnt(0)" ::: "memory");
            __builtin_amdgcn_s_barrier();
            __builtin_amdgcn_sched_barrier(0);
        }
    }

    // ---- reduce l across the lane pair (q, q+32) — R12's missing line ----
    lsum += __shfl_xor(lsum, 32);

    // ---- pair-merge through LDS (overlay on KV ring) ----
    __syncthreads();                          // all waves done with the ring
    float* mg = (float*)&KV[0][0];            // [4 pairs][34][64] floats = 34.8 KB
    if (kvh == 1) {                           // writers: upper-half waves
        const int base = g * 34 * 64;
        #pragma unroll
        for (int j = 0; j < 16; ++j) mg[base + j * 64 + lane] = ca0[j];
        #pragma unroll
        for (int j = 0; j < 16; ++j) mg[base + (16 + j) * 64 + lane] = ca1[j];
        mg[base + 32 * 64 + lane] = m_s;
        mg[base + 33 * 64 + lane] = lsum;
    }
    __syncthreads();
    if (kvh == 0) {                           // readers: merge + epilogue
        const int base = g * 34 * 64;
        const float pm = mg[base + 32 * 64 + lane];
        const float pl = mg[base + 33 * 64 + lane];
        const float mm = fmaxf(m_s, pm);
        const float fa = ex2(m_s - mm);
        const float fb = ex2(pm - mm);
        const float lm = lsum * fa + pl * fb;
        const float inv = 1.0f / lm;
        unsigned short* cg = &ctx[(size_t)(b * S_ + myq) * HID_ + h * HD_];
        #pragma unroll
        for (int m = 0; m < 4; ++m) {
            ushort4 o0;
            o0.x = f2bf((ca0[4 * m + 0] * fa + mg[base + (4 * m + 0) * 64 + lane] * fb) * inv);
            o0.y = f2bf((ca0[4 * m + 1] * fa + mg[base + (4 * m + 1) * 64 + lane] * fb) * inv);
            o0.z = f2bf((ca0[4 * m + 2] * fa + mg[base + (4 * m + 2) * 64 + lane] * fb) * inv);
            o0.w = f2bf((ca0[4 * m + 3] * fa + mg[base + (4 * m + 3) * 64 + lane] * fb) * inv);
            *(ushort4*)&cg[m * 8 + hi * 4] = o0;
            ushort4 o1;
            o1.x = f2bf((ca1[4 * m + 0] * fa + mg[base + (16 + 4 * m + 0) * 64 + lane] * fb) * inv);
            o1.y = f2bf((ca1[4 * m + 1] * fa + mg[base + (16 + 4 * m + 1) * 64 + lane] * fb) * inv);
            o1.z = f2bf((ca1[4 * m + 2] * fa + mg[base + (16 + 4 * m + 2) * 64 + lane] * fb) * inv);
            o1.w = f2bf((ca1[4 * m + 3] * fa + mg[base + (16 + 4 * m + 3) * 64 + lane] * fb) * inv);
            *(ushort4*)&cg[32 + m * 8 + hi * 4] = o1;
        }
    }
}

// ---------------- launcher ----------------
extern "C" void kernel_launch(void* const* d_in, const int* in_sizes, int n_in,
                              void* d_out, int out_size, void* d_ws, size_t ws_size,
                              hipStream_t stream) {
    const float* hs  = (const float*)d_in[0];
    const float* msk = (const float*)d_in[1];
    const float* Wq  = (const float*)d_in[2];
    const float* bq  = (const float*)d_in[3];
    const float* Wk  = (const float*)d_in[4];
    const float* bk  = (const float*)d_in[5];
    const float* Wv  = (const float*)d_in[6];
    const float* bv  = (const float*)d_in[7];
    const float* Wo  = (const float*)d_in[8];
    const float* bo  = (const float*)d_in[9];
    const float* rel = (const float*)d_in[10];
    float* out = (float*)d_out;

    char* ws = (char*)d_ws;
    unsigned short* hsb = (unsigned short*)ws; ws += (size_t)M_ * HID_ * 2;
    unsigned short* Wqt = (unsigned short*)ws; ws += (size_t)HID_ * HID_ * 2;
    unsigned short* Wkt = (unsigned short*)ws; ws += (size_t)HID_ * HID_ * 2;
    unsigned short* Wvt = (unsigned short*)ws; ws += (size_t)HID_ * HID_ * 2;
    unsigned short* Wot = (unsigned short*)ws; ws += (size_t)HID_ * HID_ * 2;
    unsigned short* Qb  = (unsigned short*)ws; ws += (size_t)M_ * HID_ * 2;
    unsigned short* Kb  = (unsigned short*)ws; ws += (size_t)M_ * HID_ * 2;
    unsigned short* Vtb = (unsigned short*)ws; ws += (size_t)M_ * HID_ * 2;
    unsigned short* ctxb= (unsigned short*)ws; ws += (size_t)M_ * HID_ * 2;
    float* maskadd      = (float*)ws;          ws += (size_t)M_ * 4;

    k_cast_hs<<<(M_ * HID_ / 4 + 255) / 256, 256, 0, stream>>>(hs, hsb, M_ * HID_ / 4);
    k_prep_mask<<<(M_ + 255) / 256, 256, 0, stream>>>(msk, maskadd);
    k_transpose_w4<<<dim3(16, 16, 4), 256, 0, stream>>>(Wq, Wk, Wv, Wo, Wqt, Wkt, Wvt, Wot);
    k_gemm_qkv<<<dim3(64, 12), 256, 0, stream>>>(
        hsb, Wqt, Wkt, Wvt, bq, bk, bv, Qb, Kb, Vtb);
    k_flash<<<512, 512, 0, stream>>>(Qb, Kb, Vtb, rel, maskadd, ctxb);
    k_gemm_out<<<dim3(64, 4), 512, 0, stream>>>(ctxb, Wot, bo, out);
}

// Round 14
// 104.934 us; speedup vs baseline: 1.0708x; 1.0532x over previous
//
#include <hip/hip_runtime.h>
#include <hip/hip_bf16.h>

#define B_    4
#define S_    2048
#define HID_  512
#define NH_   8
#define HD_   64
#define MAXREL 512
#define M_    (B_ * S_)   // 8192 tokens

#define LOG2E 1.44269504f
#define SCALE_Q (0.125f * LOG2E)   // folded into Q at projection time

typedef __attribute__((ext_vector_type(8))) short bf8;            // 8 bf16 (MFMA A/B frag)
typedef __attribute__((ext_vector_type(4))) float f4;             // 16x16 C/D frag
typedef __attribute__((ext_vector_type(16))) float f16f;          // 32x32 C/D frag

static __device__ __forceinline__ unsigned short f2bf(float f) {
    union { float f; unsigned int u; } v; v.f = f;
    unsigned int u = v.u;
    unsigned int r = (u + 0x7FFFu + ((u >> 16) & 1u)) >> 16;   // round-nearest-even
    return (unsigned short)r;
}

static __device__ __forceinline__ float ex2(float x) {   // raw v_exp_f32 (base-2)
    float r; asm("v_exp_f32 %0, %1" : "=v"(r) : "v"(x)); return r;
}

// async global->LDS, 16B per lane; dest = wave-uniform base + lane*16 (linear)
static __device__ __forceinline__ void gload16(const void* g, void* l) {
    __builtin_amdgcn_global_load_lds(
        (const __attribute__((address_space(1))) unsigned int*)g,
        (__attribute__((address_space(3))) unsigned int*)l, 16, 0, 0);
}

static __device__ __forceinline__ bf8 mkbf8(unsigned a, unsigned b, unsigned c, unsigned d) {
    uint4 u = make_uint4(a, b, c, d);
    return *(bf8*)&u;
}

#define MFMA16(a, b, c) __builtin_amdgcn_mfma_f32_16x16x32_bf16((a), (b), (c), 0, 0, 0)
#define MFMA32(a, b, c) __builtin_amdgcn_mfma_f32_32x32x16_bf16((a), (b), (c), 0, 0, 0)

// ---------------- cast hidden_states fp32 -> bf16 + mask bit-pack (block 0) ----------------
__global__ void k_cast_hs(const float* __restrict__ src, unsigned short* __restrict__ dst, int n4,
                          const float* __restrict__ mask, unsigned* __restrict__ maskbits) {
    int i = blockIdx.x * blockDim.x + threadIdx.x;
    if (i < n4) {
        float4 v = ((const float4*)src)[i];
        ushort4 o;
        o.x = f2bf(v.x); o.y = f2bf(v.y); o.z = f2bf(v.z); o.w = f2bf(v.w);
        ((ushort4*)dst)[i] = o;
    }
    if (blockIdx.x == 0 && threadIdx.x < 256) {
        const int t = threadIdx.x;
        const int b = t >> 6, wd = t & 63;
        unsigned bits = 0;
        #pragma unroll
        for (int j = 0; j < 32; ++j)
            bits |= (mask[b * S_ + wd * 32 + j] > 0.5f ? 1u : 0u) << j;
        maskbits[t] = bits;
    }
}

// ---------------- transpose + cast 4 weights (LDS 32x32 tiles) ----------------
__global__ void k_transpose_w4(const float* __restrict__ W0, const float* __restrict__ W1,
                               const float* __restrict__ W2, const float* __restrict__ W3,
                               unsigned short* __restrict__ T0, unsigned short* __restrict__ T1,
                               unsigned short* __restrict__ T2, unsigned short* __restrict__ T3) {
    __shared__ float tile[32][33];
    const int z = blockIdx.z;
    const float* W = (z == 0) ? W0 : (z == 1) ? W1 : (z == 2) ? W2 : W3;
    unsigned short* T = (z == 0) ? T0 : (z == 1) ? T1 : (z == 2) ? T2 : T3;
    const int tx = threadIdx.x & 31, ty = threadIdx.x >> 5;   // 256 thr
    const int n0 = blockIdx.x * 32, k0 = blockIdx.y * 32;
    #pragma unroll
    for (int i = 0; i < 4; ++i)
        tile[ty + i * 8][tx] = W[(size_t)(k0 + ty + i * 8) * HID_ + n0 + tx];
    __syncthreads();
    #pragma unroll
    for (int i = 0; i < 4; ++i)
        T[(size_t)(n0 + ty + i * 8) * HID_ + k0 + tx] = f2bf(tile[tx][ty + i * 8]);
}

// ---------------- fused QKV GEMM: 128x128 tile, dbuf LDS via global_load_lds ----------------
__global__ __launch_bounds__(256, 3) void k_gemm_qkv(
    const unsigned short* __restrict__ Abf,
    const unsigned short* __restrict__ Wqt, const unsigned short* __restrict__ Wkt,
    const unsigned short* __restrict__ Wvt,
    const float* __restrict__ bq, const float* __restrict__ bk, const float* __restrict__ bv,
    unsigned short* __restrict__ Q, unsigned short* __restrict__ K, unsigned short* __restrict__ Vt)
{
    __shared__ unsigned short Al[2][128 * 32];
    __shared__ unsigned short Bl[2][128 * 32];

    const int t = threadIdx.x;
    const int lane = t & 63, w = t >> 6;
    const int lr = lane & 15, lg = lane >> 4;
    const int wr = w >> 1, wc = w & 1;

    const int m0 = blockIdx.x * 128;
    const int ng = blockIdx.y * 128;
    const int z = ng >> 9;
    const int n0 = ng & 511;
    const unsigned short* Wt = (z == 0) ? Wqt : ((z == 1) ? Wkt : Wvt);
    const float* bias = (z == 0) ? bq : ((z == 1) ? bk : bv);
    const float osc = (z == 0) ? SCALE_Q : 1.0f;

    const int srow = t >> 2;
    const int sc = (((t & 3) ^ ((srow >> 1) & 3))) * 8;     // swizzled source col
    const unsigned short* Ag0 = &Abf[(size_t)(m0 + srow) * HID_ + sc];
    const unsigned short* Ag1 = &Abf[(size_t)(m0 + 64 + srow) * HID_ + sc];
    const unsigned short* Bg0 = &Wt[(size_t)(n0 + srow) * HID_ + sc];
    const unsigned short* Bg1 = &Wt[(size_t)(n0 + 64 + srow) * HID_ + sc];
    char* dA0 = (char*)&Al[0][0] + w * 1024;
    char* dB0 = (char*)&Bl[0][0] + w * 1024;

    const int fx = (lr >> 1) & 3;
    int aoff[4], boff[4];
    #pragma unroll
    for (int i = 0; i < 4; ++i) {
        aoff[i] = (wr * 64 + i * 16 + lr) * 32 + ((lg ^ fx) * 8);
        boff[i] = (wc * 64 + i * 16 + lr) * 32 + ((lg ^ fx) * 8);
    }

    gload16(Ag0, dA0);
    gload16(Ag1, dA0 + 4096);
    gload16(Bg0, dB0);
    gload16(Bg1, dB0 + 4096);
    __syncthreads();

    f4 acc[4][4] = {};
    for (int kt = 0; kt < 16; ++kt) {
        const int cur = kt & 1;
        if (kt < 15) {
            const int ko = (kt + 1) * 32;
            const int bo = (cur ^ 1) * 8192;
            gload16(Ag0 + ko, dA0 + bo);
            gload16(Ag1 + ko, dA0 + bo + 4096);
            gload16(Bg0 + ko, dB0 + bo);
            gload16(Bg1 + ko, dB0 + bo + 4096);
        }
        bf8 af[4], bf_[4];
        #pragma unroll
        for (int i = 0; i < 4; ++i) {
            af[i]  = *(const bf8*)&Al[cur][aoff[i]];
            bf_[i] = *(const bf8*)&Bl[cur][boff[i]];
        }
        #pragma unroll
        for (int mi = 0; mi < 4; ++mi)
            #pragma unroll
            for (int ni = 0; ni < 4; ++ni)
                acc[mi][ni] = MFMA16(af[mi], bf_[ni], acc[mi][ni]);
        __syncthreads();
    }

    #pragma unroll
    for (int mi = 0; mi < 4; ++mi)
    #pragma unroll
    for (int ni = 0; ni < 4; ++ni) {
        const int col = n0 + wc * 64 + ni * 16 + lr;
        const int h = col >> 6, d = col & 63;
        const float bs = bias[col];
        const int row0 = m0 + wr * 64 + mi * 16 + lg * 4;
        const int b = row0 >> 11, s0 = row0 & 2047;
        if (z == 2) {
            ushort4 o;
            o.x = f2bf(acc[mi][ni][0] + bs);
            o.y = f2bf(acc[mi][ni][1] + bs);
            o.z = f2bf(acc[mi][ni][2] + bs);
            o.w = f2bf(acc[mi][ni][3] + bs);
            *(ushort4*)&Vt[(((size_t)(b * NH_ + h)) * HD_ + d) * S_ + s0] = o;
        } else {
            unsigned short* dst = (z == 0) ? Q : K;
            #pragma unroll
            for (int r = 0; r < 4; ++r) {
                float v = (acc[mi][ni][r] + bs) * osc;
                dst[(((size_t)(b * NH_ + h)) * S_ + s0 + r) * HD_ + d] = f2bf(v);
            }
        }
    }
}

// ---------------- output projection GEMM: 128x128 tile, 512 threads ----------------
__global__ __launch_bounds__(512) void k_gemm_out(
    const unsigned short* __restrict__ Abf,
    const unsigned short* __restrict__ Wot,
    const float* __restrict__ bo,
    float* __restrict__ out)
{
    __shared__ unsigned short Al[2][128 * 32];
    __shared__ unsigned short Bl[2][128 * 32];

    const int t = threadIdx.x;
    const int lane = t & 63, w = t >> 6;          // 8 waves, 2x4
    const int lr = lane & 15, lg = lane >> 4;
    const int wr = w >> 2, wc = w & 3;

    const int m0 = blockIdx.x * 128;
    const int n0 = blockIdx.y * 128;

    const int srow = t >> 2;
    const int sc = (((t & 3) ^ ((srow >> 1) & 3))) * 8;
    const unsigned short* Ag = &Abf[(size_t)(m0 + srow) * HID_ + sc];
    const unsigned short* Bg = &Wot[(size_t)(n0 + srow) * HID_ + sc];
    char* dA = (char*)&Al[0][0] + w * 1024;
    char* dB = (char*)&Bl[0][0] + w * 1024;

    const int fx = (lr >> 1) & 3;
    int aoff[4], boff[2];
    #pragma unroll
    for (int i = 0; i < 4; ++i)
        aoff[i] = (wr * 64 + i * 16 + lr) * 32 + ((lg ^ fx) * 8);
    #pragma unroll
    for (int i = 0; i < 2; ++i)
        boff[i] = (wc * 32 + i * 16 + lr) * 32 + ((lg ^ fx) * 8);

    gload16(Ag, dA);
    gload16(Bg, dB);
    __syncthreads();

    f4 acc[4][2] = {};
    for (int kt = 0; kt < 16; ++kt) {
        const int cur = kt & 1;
        if (kt < 15) {
            const int ko = (kt + 1) * 32;
            const int bo_ = (cur ^ 1) * 8192;
            gload16(Ag + ko, dA + bo_);
            gload16(Bg + ko, dB + bo_);
        }
        bf8 af[4], bf_[2];
        #pragma unroll
        for (int i = 0; i < 4; ++i) af[i] = *(const bf8*)&Al[cur][aoff[i]];
        #pragma unroll
        for (int i = 0; i < 2; ++i) bf_[i] = *(const bf8*)&Bl[cur][boff[i]];
        #pragma unroll
        for (int mi = 0; mi < 4; ++mi)
            #pragma unroll
            for (int ni = 0; ni < 2; ++ni)
                acc[mi][ni] = MFMA16(af[mi], bf_[ni], acc[mi][ni]);
        __syncthreads();
    }

    #pragma unroll
    for (int mi = 0; mi < 4; ++mi)
    #pragma unroll
    for (int ni = 0; ni < 2; ++ni) {
        const int col = n0 + wc * 32 + ni * 16 + lr;
        const float bs = bo[col];
        const int row0 = m0 + wr * 64 + mi * 16 + lg * 4;
        #pragma unroll
        for (int r = 0; r < 4; ++r)
            out[(size_t)(row0 + r) * HID_ + col] = acc[mi][ni][r] + bs;
    }
}

// ---------------- flash attention: 8 waves = 4 q-groups x 2 kv-halves, mfma 32x32x16.
//   R13 structure + mask as register bitmask (scalar fast-path skip), no maskc LDS. ----------------
__global__ __launch_bounds__(512, 4) void k_flash(
    const unsigned short* __restrict__ Q, const unsigned short* __restrict__ K,
    const unsigned short* __restrict__ Vt,
    const float* __restrict__ rel_table, const unsigned* __restrict__ maskbits,
    unsigned short* __restrict__ ctx)
{
    __shared__ unsigned short KV[3][8192];   // per buf: [0,4096) ushorts K, [4096,8192) V
    __shared__ float Tw[1216];               // bias window, rel in [-605,605], pre-clipped, *log2e

    const int t = threadIdx.x;
    const int lane = t & 63, w = t >> 6;     // 8 waves
    const int q = lane & 31, hi = lane >> 5;
    const int g = w & 3, kvh = w >> 2;       // q-group, kv-half

    // bijective XCD swizzle: each XCD owns 4 complete (b,h) pairs
    const int flat = blockIdx.x;             // 0..511
    const int idx = flat >> 3;
    const int bh = (flat & 7) * 4 + (idx >> 4);
    const int qb = idx & 15;
    const int b = bh >> 3, h = bh & 7;
    const int q0 = qb * 128;

    // mask words for this wave's kv windows: lane ti (<32) holds word for tile ti
    unsigned mword = 0xFFFFFFFFu;
    if (lane < 32) mword = maskbits[b * 64 + 2 * lane + kvh];

    for (int i = t; i < 1216; i += 512) {
        int r = i - 606;
        r = r < -MAXREL ? -MAXREL : (r > MAXREL ? MAXREL : r);
        Tw[i] = rel_table[(r + MAXREL) * NH_ + h] * LOG2E;
    }
    const float TbLo = rel_table[h] * LOG2E;                    // rel = -512
    const float TbHi = rel_table[2 * MAXREL * NH_ + h] * LOG2E; // rel = +512

    const unsigned short* Kb = K + (size_t)bh * S_ * HD_;
    const unsigned short* Vb = Vt + (size_t)bh * HD_ * S_;

    const int myq = q0 + g * 32 + q;
    const int qw = q0 + g * 32;
    bf8 qf[4];   // B-frag: col=q, k(d)=16s+8hi+j
    #pragma unroll
    for (int s = 0; s < 4; ++s)
        qf[s] = *(const bf8*)&Q[((size_t)bh * S_ + myq) * HD_ + s * 16 + hi * 8];

    // staging (512 thr): thread t -> row t>>3 (0..63), slot t&7; source col pre-swizzled
    const int srow = t >> 3, sslot = t & 7;
    const int sxor = (sslot ^ (srow & 7)) * 8;
    const size_t kb0 = (size_t)srow * HD_ + sxor;
    const size_t vb0 = (size_t)srow * S_ + sxor;
    const int woff = w * 1024;               // wave's linear 1KB chunk (8 rows x 128B)

    auto stage = [&](int kvt, int buf) {
        char* base = (char*)&KV[buf][0];
        gload16(&Kb[kb0 + (size_t)kvt * 64 * HD_], base + woff);
        gload16(&Vb[vb0 + (size_t)kvt * 64], base + 8192 + woff);
    };

    f16f ca0 = {}, ca1 = {};       // ctx^T partial: col=q, d = {0,32} + (reg&3)+8*(reg>>2)+4hi
    float m_s = -INFINITY, lsum = 0.f;

    // prologue: 2 tiles in flight (2 loads/wave each)
    stage(0, 0);
    stage(1, 1);
    asm volatile("s_waitcnt lgkmcnt(0)" ::: "memory");   // Tw ds_writes drained
    asm volatile("s_waitcnt vmcnt(2)" ::: "memory");     // buf0 ready
    __builtin_amdgcn_s_barrier();
    __builtin_amdgcn_sched_barrier(0);

    const int xq = q & 7;
    // Tw index: 606 + key - myq; key = kv0 + 32*kvh + 8m + 4hi + r
    const int jb0 = 606 + 32 * kvh + 4 * hi - q0 - g * 32 - q;   // + kv0 + 8m + r
    for (int ti = 0; ti < 32; ++ti) {
        const int kv0 = ti * 64;
        const int cur = ti % 3;
        const int kvs = kv0 + 32 * kvh;      // this wave's 32-key window

        if (ti < 30) stage(ti + 2, (ti + 2) % 3);

        const unsigned short* Kt  = &KV[cur][0];
        const unsigned short* Vtl = &KV[cur][4096];

        // ---- QK^T (swapped): C[key_local][q], this wave's 32 keys ----
        f16f sa = {};
        __builtin_amdgcn_s_setprio(1);
        #pragma unroll
        for (int s = 0; s < 4; ++s) {
            bf8 kf = *(const bf8*)&Kt[(32 * kvh + q) * 64 + (((2 * s + hi) ^ xq) * 8)];
            sa = MFMA32(kf, qf[s], sa);
        }
        __builtin_amdgcn_s_setprio(0);

        // ---- mask (rare slow path; scalar-uniform skip when all-attend) ----
        const unsigned mws = __builtin_amdgcn_readlane(mword, ti);
        if (mws != 0xFFFFFFFFu) {
            #pragma unroll
            for (int m = 0; m < 4; ++m) {
                const unsigned tb = mws >> (8 * m + 4 * hi);
                #pragma unroll
                for (int r = 0; r < 4; ++r)
                    sa[4 * m + r] += ((tb >> r) & 1) ? 0.f : -3.0e38f;
            }
        }

        // ---- bias + row max (4 parallel max accumulators) ----
        float t0 = -INFINITY, t1 = -INFINITY, t2 = -INFINITY, t3 = -INFINITY;
        {
            const bool ulo = (kvs + 31 - qw <= -MAXREL);
            const bool uhi = (kvs - (qw + 31) >= MAXREL);
            if (ulo || uhi) {
                const float bc = ulo ? TbLo : TbHi;
                #pragma unroll
                for (int m = 0; m < 4; ++m) {
                    float s0 = sa[4 * m + 0] + bc;  sa[4 * m + 0] = s0;  t0 = fmaxf(t0, s0);
                    float s1 = sa[4 * m + 1] + bc;  sa[4 * m + 1] = s1;  t1 = fmaxf(t1, s1);
                    float s2 = sa[4 * m + 2] + bc;  sa[4 * m + 2] = s2;  t2 = fmaxf(t2, s2);
                    float s3 = sa[4 * m + 3] + bc;  sa[4 * m + 3] = s3;  t3 = fmaxf(t3, s3);
                }
            } else {
                #pragma unroll
                for (int m = 0; m < 4; ++m) {
                    const int jb = jb0 + kv0 + m * 8;
                    float s0 = sa[4 * m + 0] + Tw[jb + 0];  sa[4 * m + 0] = s0;  t0 = fmaxf(t0, s0);
                    float s1 = sa[4 * m + 1] + Tw[jb + 1];  sa[4 * m + 1] = s1;  t1 = fmaxf(t1, s1);
                    float s2 = sa[4 * m + 2] + Tw[jb + 2];  sa[4 * m + 2] = s2;  t2 = fmaxf(t2, s2);
                    float s3 = sa[4 * m + 3] + Tw[jb + 3];  sa[4 * m + 3] = s3;  t3 = fmaxf(t3, s3);
                }
            }
        }
        float tmaxl = fmaxf(fmaxf(t0, t1), fmaxf(t2, t3));
        const float tmax = fmaxf(tmaxl, __shfl_xor(tmaxl, 32));   // row = lanes q, q+32

        // ---- speculative exp with current m_s (defer-max common case) ----
        float ptile = 0.f;
        unsigned int pk[8];
        #pragma unroll
        for (int m = 0; m < 4; ++m) {
            float a0 = ex2(sa[4 * m + 0] - m_s), a1 = ex2(sa[4 * m + 1] - m_s);
            float a2 = ex2(sa[4 * m + 2] - m_s), a3 = ex2(sa[4 * m + 3] - m_s);
            ptile += (a0 + a1) + (a2 + a3);
            asm("v_cvt_pk_bf16_f32 %0, %1, %2" : "=v"(pk[2 * m])     : "v"(a0), "v"(a1));
            asm("v_cvt_pk_bf16_f32 %0, %1, %2" : "=v"(pk[2 * m + 1]) : "v"(a2), "v"(a3));
        }
        if (!__all(tmax <= m_s + 8.0f)) {     // rare: rescale + recompute
            const float mnew = fmaxf(m_s, tmax);
            const float fac = ex2(m_s - mnew);
            lsum *= fac;
            ca0 *= fac;
            ca1 *= fac;
            ptile = 0.f;
            #pragma unroll
            for (int m = 0; m < 4; ++m) {
                float a0 = ex2(sa[4 * m + 0] - mnew), a1 = ex2(sa[4 * m + 1] - mnew);
                float a2 = ex2(sa[4 * m + 2] - mnew), a3 = ex2(sa[4 * m + 3] - mnew);
                ptile += (a0 + a1) + (a2 + a3);
                asm("v_cvt_pk_bf16_f32 %0, %1, %2" : "=v"(pk[2 * m])     : "v"(a0), "v"(a1));
                asm("v_cvt_pk_bf16_f32 %0, %1, %2" : "=v"(pk[2 * m + 1]) : "v"(a2), "v"(a3));
            }
            m_s = mnew;
        }
        lsum += ptile;

        // ---- P B-frags via permlane32_swap (kv-local [0,32)) ----
        bf8 pf0, pf1;
        {
            unsigned c0 = pk[0], c2 = pk[2], c1 = pk[1], c3 = pk[3];
            asm("v_permlane32_swap_b32 %0, %1" : "+v"(c0), "+v"(c2));
            asm("v_permlane32_swap_b32 %0, %1" : "+v"(c1), "+v"(c3));
            pf0 = mkbf8(c0, c1, c2, c3);
        }
        {
            unsigned c0 = pk[4], c2 = pk[6], c1 = pk[5], c3 = pk[7];
            asm("v_permlane32_swap_b32 %0, %1" : "+v"(c0), "+v"(c2));
            asm("v_permlane32_swap_b32 %0, %1" : "+v"(c1), "+v"(c3));
            pf1 = mkbf8(c0, c1, c2, c3);
        }

        // ---- PV (swapped): C[d][q] += mfma32(V^T frag, P frag), kv = this half ----
        __builtin_amdgcn_s_setprio(1);
        #pragma unroll
        for (int s = 0; s < 2; ++s) {
            const int slot = ((4 * kvh + 2 * s + hi) ^ xq) * 8;
            bf8 v0 = *(const bf8*)&Vtl[q * 64 + slot];
            bf8 v1 = *(const bf8*)&Vtl[(q + 32) * 64 + slot];
            bf8 pf = (s == 0) ? pf0 : pf1;
            ca0 = MFMA32(v0, pf, ca0);
            ca1 = MFMA32(v1, pf, ca1);
        }
        __builtin_amdgcn_s_setprio(0);

        // ---- counted-vmcnt barrier ----
        if (ti < 31) {
            if (ti < 30) asm volatile("s_waitcnt vmcnt(2)" ::: "memory");
            else         asm volatile("s_waitcnt vmcnt(0)" ::: "memory");
            __builtin_amdgcn_s_barrier();
            __builtin_amdgcn_sched_barrier(0);
        }
    }

    // ---- reduce l across the lane pair (q, q+32) ----
    lsum += __shfl_xor(lsum, 32);

    // ---- pair-merge through LDS (overlay on KV ring) ----
    __syncthreads();                          // all waves done with the ring
    float* mg = (float*)&KV[0][0];            // [4 pairs][34][64] floats = 34.8 KB
    if (kvh == 1) {                           // writers: upper-half waves
        const int base = g * 34 * 64;
        #pragma unroll
        for (int j = 0; j < 16; ++j) mg[base + j * 64 + lane] = ca0[j];
        #pragma unroll
        for (int j = 0; j < 16; ++j) mg[base + (16 + j) * 64 + lane] = ca1[j];
        mg[base + 32 * 64 + lane] = m_s;
        mg[base + 33 * 64 + lane] = lsum;
    }
    __syncthreads();
    if (kvh == 0) {                           // readers: merge + epilogue
        const int base = g * 34 * 64;
        const float pm = mg[base + 32 * 64 + lane];
        const float pl = mg[base + 33 * 64 + lane];
        const float mm = fmaxf(m_s, pm);
        const float fa = ex2(m_s - mm);
        const float fb = ex2(pm - mm);
        const float lm = lsum * fa + pl * fb;
        const float inv = 1.0f / lm;
        unsigned short* cg = &ctx[(size_t)(b * S_ + myq) * HID_ + h * HD_];
        #pragma unroll
        for (int m = 0; m < 4; ++m) {
            ushort4 o0;
            o0.x = f2bf((ca0[4 * m + 0] * fa + mg[base + (4 * m + 0) * 64 + lane] * fb) * inv);
            o0.y = f2bf((ca0[4 * m + 1] * fa + mg[base + (4 * m + 1) * 64 + lane] * fb) * inv);
            o0.z = f2bf((ca0[4 * m + 2] * fa + mg[base + (4 * m + 2) * 64 + lane] * fb) * inv);
            o0.w = f2bf((ca0[4 * m + 3] * fa + mg[base + (4 * m + 3) * 64 + lane] * fb) * inv);
            *(ushort4*)&cg[m * 8 + hi * 4] = o0;
            ushort4 o1;
            o1.x = f2bf((ca1[4 * m + 0] * fa + mg[base + (16 + 4 * m + 0) * 64 + lane] * fb) * inv);
            o1.y = f2bf((ca1[4 * m + 1] * fa + mg[base + (16 + 4 * m + 1) * 64 + lane] * fb) * inv);
            o1.z = f2bf((ca1[4 * m + 2] * fa + mg[base + (16 + 4 * m + 2) * 64 + lane] * fb) * inv);
            o1.w = f2bf((ca1[4 * m + 3] * fa + mg[base + (16 + 4 * m + 3) * 64 + lane] * fb) * inv);
            *(ushort4*)&cg[32 + m * 8 + hi * 4] = o1;
        }
    }
}

// ---------------- launcher ----------------
extern "C" void kernel_launch(void* const* d_in, const int* in_sizes, int n_in,
                              void* d_out, int out_size, void* d_ws, size_t ws_size,
                              hipStream_t stream) {
    const float* hs  = (const float*)d_in[0];
    const float* msk = (const float*)d_in[1];
    const float* Wq  = (const float*)d_in[2];
    const float* bq  = (const float*)d_in[3];
    const float* Wk  = (const float*)d_in[4];
    const float* bk  = (const float*)d_in[5];
    const float* Wv  = (const float*)d_in[6];
    const float* bv  = (const float*)d_in[7];
    const float* Wo  = (const float*)d_in[8];
    const float* bo  = (const float*)d_in[9];
    const float* rel = (const float*)d_in[10];
    float* out = (float*)d_out;

    char* ws = (char*)d_ws;
    unsigned short* hsb = (unsigned short*)ws; ws += (size_t)M_ * HID_ * 2;
    unsigned short* Wqt = (unsigned short*)ws; ws += (size_t)HID_ * HID_ * 2;
    unsigned short* Wkt = (unsigned short*)ws; ws += (size_t)HID_ * HID_ * 2;
    unsigned short* Wvt = (unsigned short*)ws; ws += (size_t)HID_ * HID_ * 2;
    unsigned short* Wot = (unsigned short*)ws; ws += (size_t)HID_ * HID_ * 2;
    unsigned short* Qb  = (unsigned short*)ws; ws += (size_t)M_ * HID_ * 2;
    unsigned short* Kb  = (unsigned short*)ws; ws += (size_t)M_ * HID_ * 2;
    unsigned short* Vtb = (unsigned short*)ws; ws += (size_t)M_ * HID_ * 2;
    unsigned short* ctxb= (unsigned short*)ws; ws += (size_t)M_ * HID_ * 2;
    unsigned* maskbits  = (unsigned*)ws;       ws += (size_t)B_ * 64 * 4;

    k_cast_hs<<<(M_ * HID_ / 4 + 255) / 256, 256, 0, stream>>>(
        hs, hsb, M_ * HID_ / 4, msk, maskbits);
    k_transpose_w4<<<dim3(16, 16, 4), 256, 0, stream>>>(Wq, Wk, Wv, Wo, Wqt, Wkt, Wvt, Wot);
    k_gemm_qkv<<<dim3(64, 12), 256, 0, stream>>>(
        hsb, Wqt, Wkt, Wvt, bq, bk, bv, Qb, Kb, Vtb);
    k_flash<<<512, 512, 0, stream>>>(Qb, Kb, Vtb, rel, maskbits, ctxb);
    k_gemm_out<<<dim3(64, 4), 512, 0, stream>>>(ctxb, Wot, bo, out);
}